// Round 1
// baseline (208.397 us; speedup 1.0000x reference)
//
#include <hip/hip_runtime.h>

typedef unsigned short u16;
typedef unsigned int u32;
typedef __attribute__((ext_vector_type(8))) short bf16x8;
typedef __attribute__((ext_vector_type(4))) float f32x4;

__device__ __forceinline__ u16 f2bf(float f) {
    union { float f; u32 u; } x; x.f = f;
    u32 r = x.u + 0x7FFFu + ((x.u >> 16) & 1u);   // RNE
    return (u16)(r >> 16);
}

__device__ __forceinline__ void gload16(const u16* g, u16* l) {
    __builtin_amdgcn_global_load_lds(
        (const __attribute__((address_space(1))) void*)g,
        (__attribute__((address_space(3))) void*)l,
        16, 0, 0);
}

__device__ __forceinline__ f32x4 mfma16(bf16x8 a, bf16x8 b, f32x4 c) {
    return __builtin_amdgcn_mfma_f32_16x16x32_bf16(a, b, c, 0, 0, 0);
}

// ---------------- prep kernels ----------------

__global__ __launch_bounds__(256) void cvt_x(const float* __restrict__ in, u16* __restrict__ out, int n4) {
    int i = blockIdx.x * blockDim.x + threadIdx.x;
    if (i >= n4) return;
    float4 v = ((const float4*)in)[i];
    u16* o = out + (size_t)i * 4;
    o[0] = f2bf(v.x); o[1] = f2bf(v.y); o[2] = f2bf(v.z); o[3] = f2bf(v.w);
}

// in: [1024][1024] f32 row-major ([k][n]); out: [1024][1024] bf16 = in^T ([n][k])
__global__ __launch_bounds__(256) void transpose_w(const float* __restrict__ in, u16* __restrict__ out) {
    __shared__ float tile[32][33];
    const int bx = blockIdx.x * 32, by = blockIdx.y * 32;
    const int tx = threadIdx.x & 31, ty4 = (threadIdx.x >> 5) * 4;
#pragma unroll
    for (int j = 0; j < 4; ++j)
        tile[ty4 + j][tx] = in[(size_t)(by + ty4 + j) * 1024 + bx + tx];
    __syncthreads();
#pragma unroll
    for (int j = 0; j < 4; ++j)
        out[(size_t)(bx + ty4 + j) * 1024 + by + tx] = f2bf(tile[tx][ty4 + j]);
}

__global__ __launch_bounds__(256) void pack_bias(const float* __restrict__ bq, const float* __restrict__ bk,
                                                 const float* __restrict__ bv, float* __restrict__ out) {
    int i = blockIdx.x * blockDim.x + threadIdx.x;
    if (i >= 3072) return;
    out[i] = (i < 1024) ? bq[i] : ((i < 2048) ? bk[i - 1024] : bv[i - 2048]);
}

// ---------------- GEMM: C[M x N] = A[M x K] @ Bt[N x K]^T + bias ----------------
// MODE 0: QKV projection (N=3072), writes Q (scaled 1/8), K, Vt in bf16 attention layouts.
// MODE 1: output projection (N=1024), writes fp32 out + bias.
template<int MODE>
__global__ __launch_bounds__(256) void gemm128(const u16* __restrict__ A, const u16* __restrict__ Bt,
                                               const float* __restrict__ bias,
                                               u16* __restrict__ oq, u16* __restrict__ ok, u16* __restrict__ ov,
                                               float* __restrict__ of, int K)
{
    __shared__ u16 As[128 * 32];
    __shared__ u16 Bs[128 * 32];

    const int n0 = blockIdx.x * 128;
    const int m0 = blockIdx.y * 128;
    const int t = threadIdx.x;
    const int w = t >> 6, lane = t & 63;
    const int g = lane >> 4, lr = lane & 15;
    const int wm = w >> 1, wn = w & 1;
    const int srow = lane >> 2;          // row within 16-row chunk
    const int scol = (lane & 3) * 8;     // element col within 32

    f32x4 acc[4][4] = {};

    for (int k0 = 0; k0 < K; k0 += 32) {
        __syncthreads();
#pragma unroll
        for (int i = 0; i < 2; ++i) {
            const int c = w + i * 4;            // chunk 0..7 (16 rows each)
            const int mrow = c * 16 + srow;
            gload16(A  + (size_t)(m0 + mrow) * K + k0 + scol, &As[c * 512 + lane * 8]);
            gload16(Bt + (size_t)(n0 + mrow) * K + k0 + scol, &Bs[c * 512 + lane * 8]);
        }
        __syncthreads();
        bf16x8 af[4], bfr[4];
#pragma unroll
        for (int mi = 0; mi < 4; ++mi) af[mi]  = *(const bf16x8*)&As[(wm * 64 + mi * 16 + lr) * 32 + g * 8];
#pragma unroll
        for (int ni = 0; ni < 4; ++ni) bfr[ni] = *(const bf16x8*)&Bs[(wn * 64 + ni * 16 + lr) * 32 + g * 8];
#pragma unroll
        for (int mi = 0; mi < 4; ++mi)
#pragma unroll
            for (int ni = 0; ni < 4; ++ni)
                acc[mi][ni] = mfma16(af[mi], bfr[ni], acc[mi][ni]);
    }

#pragma unroll
    for (int mi = 0; mi < 4; ++mi) {
#pragma unroll
        for (int ni = 0; ni < 4; ++ni) {
            const int col = n0 + wn * 64 + ni * 16 + lr;
            const int row0 = m0 + wm * 64 + mi * 16 + g * 4;
            const float bs = bias[col];
            if (MODE == 0) {
                const int mat = col >> 10;
                const int nn = col & 1023;
                const int h = nn >> 6, d = nn & 63;
#pragma unroll
                for (int j = 0; j < 4; ++j) {
                    const int rr = row0 + j;
                    const int b = rr >> 11, ll = rr & 2047;
                    const int bh = b * 16 + h;
                    const float v = acc[mi][ni][j] + bs;
                    if (mat == 0)      oq[((size_t)bh * 2048 + ll) * 64 + d] = f2bf(v * 0.125f);
                    else if (mat == 1) ok[((size_t)bh * 2048 + ll) * 64 + d] = f2bf(v);
                    else               ov[((size_t)bh * 64 + d) * 2048 + ll] = f2bf(v);
                }
            } else {
#pragma unroll
                for (int j = 0; j < 4; ++j) {
                    const int rr = row0 + j;
                    of[(size_t)rr * 1024 + col] = acc[mi][ni][j] + bs;
                }
            }
        }
    }
}

// ---------------- flash attention (causal) ----------------
// Q,K: [32 bh][2048][64] bf16 (Q pre-scaled by 1/8).  Vt: [32 bh][64][2048] bf16.
// O: [b][l][1024] bf16 (= [b,l,h*64+d]).
__global__ __launch_bounds__(256) void attn(const u16* __restrict__ Q, const u16* __restrict__ Kg,
                                            const u16* __restrict__ Vt, u16* __restrict__ O)
{
    __shared__ u16 Ks[64][72];
    __shared__ u16 Vs[64][72];
    __shared__ u16 Ps[4][32][72];

    const int bh = blockIdx.y;
    const int qb = blockIdx.x;
    const int q0 = qb * 128;
    const int t = threadIdx.x;
    const int w = t >> 6, lane = t & 63;
    const int g = lane >> 4, lr = lane & 15;
    const int qw = q0 + w * 32;

    const u16* Qb = Q  + (size_t)bh * 2048 * 64;
    const u16* Kb = Kg + (size_t)bh * 2048 * 64;
    const u16* Vb = Vt + (size_t)bh * 64 * 2048;

    bf16x8 qfr[2][2];
#pragma unroll
    for (int qf = 0; qf < 2; ++qf)
#pragma unroll
        for (int ks = 0; ks < 2; ++ks)
            qfr[qf][ks] = *(const bf16x8*)&Qb[(size_t)(qw + qf * 16 + lr) * 64 + ks * 32 + g * 8];

    f32x4 oacc[2][4] = {};
    float mrun[2][4], lrun[2][4];
#pragma unroll
    for (int qf = 0; qf < 2; ++qf)
#pragma unroll
        for (int j = 0; j < 4; ++j) { mrun[qf][j] = -1e30f; lrun[qf][j] = 0.f; }

    const int nkb = (q0 + 128) >> 6;
    for (int kb = 0; kb < nkb; ++kb) {
        const int k0 = kb * 64;
        __syncthreads();
        // stage K tile [64][64] and Vt tile [64][64] (reg-staged, padded rows)
#pragma unroll
        for (int i = 0; i < 2; ++i) {
            const int c = t + i * 256;          // 0..511
            const int row = c >> 3;
            const int c8 = (c & 7) * 8;
            *(bf16x8*)&Ks[row][c8] = *(const bf16x8*)&Kb[(size_t)(k0 + row) * 64 + c8];
            *(bf16x8*)&Vs[row][c8] = *(const bf16x8*)&Vb[(size_t)row * 2048 + k0 + c8];
        }
        __syncthreads();

        // S = (Q/8) @ K^T : [32 q x 64 k] per wave
        f32x4 s[2][4] = {};
#pragma unroll
        for (int ni = 0; ni < 4; ++ni) {
            bf16x8 kf0 = *(const bf16x8*)&Ks[ni * 16 + lr][g * 8];
            bf16x8 kf1 = *(const bf16x8*)&Ks[ni * 16 + lr][32 + g * 8];
#pragma unroll
            for (int qf = 0; qf < 2; ++qf) {
                s[qf][ni] = mfma16(qfr[qf][0], kf0, s[qf][ni]);
                s[qf][ni] = mfma16(qfr[qf][1], kf1, s[qf][ni]);
            }
        }
        // causal mask (only when the tile straddles/exceeds the diagonal)
        if (k0 + 63 > qw) {
#pragma unroll
            for (int qf = 0; qf < 2; ++qf)
#pragma unroll
                for (int ni = 0; ni < 4; ++ni)
#pragma unroll
                    for (int j = 0; j < 4; ++j) {
                        const int kk = k0 + ni * 16 + lr;
                        const int qq = qw + qf * 16 + g * 4 + j;
                        if (kk > qq) s[qf][ni][j] = -1e30f;
                    }
        }
        // online softmax (wave-parallel row reduce over the 16 lanes holding each row)
#pragma unroll
        for (int qf = 0; qf < 2; ++qf) {
#pragma unroll
            for (int j = 0; j < 4; ++j) {
                float pm = fmaxf(fmaxf(s[qf][0][j], s[qf][1][j]), fmaxf(s[qf][2][j], s[qf][3][j]));
                pm = fmaxf(pm, __shfl_xor(pm, 1));
                pm = fmaxf(pm, __shfl_xor(pm, 2));
                pm = fmaxf(pm, __shfl_xor(pm, 4));
                pm = fmaxf(pm, __shfl_xor(pm, 8));
                const float mn = fmaxf(mrun[qf][j], pm);
                const float r = __expf(mrun[qf][j] - mn);
                float rs = 0.f;
#pragma unroll
                for (int ni = 0; ni < 4; ++ni) {
                    const float p = __expf(s[qf][ni][j] - mn);
                    rs += p;
                    Ps[w][qf * 16 + g * 4 + j][ni * 16 + lr] = f2bf(p);
                }
                rs += __shfl_xor(rs, 1);
                rs += __shfl_xor(rs, 2);
                rs += __shfl_xor(rs, 4);
                rs += __shfl_xor(rs, 8);
                lrun[qf][j] = lrun[qf][j] * r + rs;
                mrun[qf][j] = mn;
#pragma unroll
                for (int df = 0; df < 4; ++df) oacc[qf][df][j] *= r;
            }
        }
        __syncthreads();   // orders per-wave P writes before P reads (drains lgkmcnt)

        // O += P @ V : B-frag from Vt (contiguous along l)
#pragma unroll
        for (int df = 0; df < 4; ++df) {
            bf16x8 vf0 = *(const bf16x8*)&Vs[df * 16 + lr][g * 8];
            bf16x8 vf1 = *(const bf16x8*)&Vs[df * 16 + lr][32 + g * 8];
#pragma unroll
            for (int qf = 0; qf < 2; ++qf) {
                bf16x8 p0 = *(const bf16x8*)&Ps[w][qf * 16 + lr][g * 8];
                bf16x8 p1 = *(const bf16x8*)&Ps[w][qf * 16 + lr][32 + g * 8];
                oacc[qf][df] = mfma16(p0, vf0, oacc[qf][df]);
                oacc[qf][df] = mfma16(p1, vf1, oacc[qf][df]);
            }
        }
    }

    // epilogue: normalize and store to [b][l][h*64+d]
    const int b = bh >> 4, h = bh & 15;
#pragma unroll
    for (int qf = 0; qf < 2; ++qf) {
#pragma unroll
        for (int j = 0; j < 4; ++j) {
            const float inv = 1.f / lrun[qf][j];
            const int l = qw + qf * 16 + g * 4 + j;
#pragma unroll
            for (int df = 0; df < 4; ++df)
                O[((size_t)b * 2048 + l) * 1024 + h * 64 + df * 16 + lr] = f2bf(oacc[qf][df][j] * inv);
        }
    }
}

// ---------------- launch ----------------

extern "C" void kernel_launch(void* const* d_in, const int* in_sizes, int n_in,
                              void* d_out, int out_size, void* d_ws, size_t ws_size,
                              hipStream_t stream)
{
    const float* hs = (const float*)d_in[0];
    const float* Wq = (const float*)d_in[1];
    const float* bq = (const float*)d_in[2];
    const float* Wk = (const float*)d_in[3];
    const float* bk = (const float*)d_in[4];
    const float* Wv = (const float*)d_in[5];
    const float* bv = (const float*)d_in[6];
    const float* Wo = (const float*)d_in[7];
    const float* bo = (const float*)d_in[8];
    float* out = (float*)d_out;

    char* ws = (char*)d_ws;
    u16*   Xbf   = (u16*)(ws);                     // 8 MB, reused as Abuf after QKV GEMM
    u16*   Wqkvt = (u16*)(ws + (8ull  << 20));     // 6 MB
    u16*   Wot   = (u16*)(ws + (14ull << 20));     // 2 MB
    float* bqkv  = (float*)(ws + (16ull << 20));   // 12 KB
    u16*   Qbuf  = (u16*)(ws + (17ull << 20));     // 8 MB
    u16*   Kbuf  = (u16*)(ws + (25ull << 20));     // 8 MB
    u16*   Vtbuf = (u16*)(ws + (33ull << 20));     // 8 MB
    u16*   Abuf  = Xbf;                            // alias: X dead after QKV GEMM

    cvt_x<<<4096, 256, 0, stream>>>(hs, Xbf, 4096 * 1024 / 4);
    transpose_w<<<dim3(32, 32), 256, 0, stream>>>(Wq, Wqkvt);
    transpose_w<<<dim3(32, 32), 256, 0, stream>>>(Wk, Wqkvt + 1024 * 1024);
    transpose_w<<<dim3(32, 32), 256, 0, stream>>>(Wv, Wqkvt + 2 * 1024 * 1024);
    transpose_w<<<dim3(32, 32), 256, 0, stream>>>(Wo, Wot);
    pack_bias<<<12, 256, 0, stream>>>(bq, bk, bv, bqkv);

    // QKV: [4096 x 3072]
    gemm128<0><<<dim3(24, 32), 256, 0, stream>>>(Xbf, Wqkvt, bqkv, Qbuf, Kbuf, Vtbuf, nullptr, 1024);
    // attention
    attn<<<dim3(16, 32), 256, 0, stream>>>(Qbuf, Kbuf, Vtbuf, Abuf);
    // output projection: [4096 x 1024] -> fp32 d_out
    gemm128<1><<<dim3(8, 32), 256, 0, stream>>>(Abuf, Wot, bo, nullptr, nullptr, nullptr, out, 1024);
}

// Round 2
// 154.636 us; speedup vs baseline: 1.3477x; 1.3477x over previous
//
#include <hip/hip_runtime.h>

typedef unsigned short u16;
typedef unsigned int u32;
typedef __attribute__((ext_vector_type(8))) short bf16x8;
typedef __attribute__((ext_vector_type(4))) float f32x4;

__device__ __forceinline__ u16 f2bf(float f) {
    union { float f; u32 u; } x; x.f = f;
    u32 r = x.u + 0x7FFFu + ((x.u >> 16) & 1u);   // RNE
    return (u16)(r >> 16);
}

__device__ __forceinline__ void gload16(const u16* g, u16* l) {
    __builtin_amdgcn_global_load_lds(
        (const __attribute__((address_space(1))) void*)g,
        (__attribute__((address_space(3))) void*)l,
        16, 0, 0);
}

__device__ __forceinline__ f32x4 mfma16(bf16x8 a, bf16x8 b, f32x4 c) {
    return __builtin_amdgcn_mfma_f32_16x16x32_bf16(a, b, c, 0, 0, 0);
}

// ---------------- prep kernels ----------------

__global__ __launch_bounds__(256) void cvt_x(const float* __restrict__ in, u16* __restrict__ out, int n4) {
    int i = blockIdx.x * blockDim.x + threadIdx.x;
    if (i >= n4) return;
    float4 v = ((const float4*)in)[i];
    u16* o = out + (size_t)i * 4;
    o[0] = f2bf(v.x); o[1] = f2bf(v.y); o[2] = f2bf(v.z); o[3] = f2bf(v.w);
}

// in: [1024][1024] f32 row-major ([k][n]); out: [1024][1024] bf16 = in^T ([n][k])
__global__ __launch_bounds__(256) void transpose_w(const float* __restrict__ in, u16* __restrict__ out) {
    __shared__ float tile[32][33];
    const int bx = blockIdx.x * 32, by = blockIdx.y * 32;
    const int tx = threadIdx.x & 31, ty4 = (threadIdx.x >> 5) * 4;
#pragma unroll
    for (int j = 0; j < 4; ++j)
        tile[ty4 + j][tx] = in[(size_t)(by + ty4 + j) * 1024 + bx + tx];
    __syncthreads();
#pragma unroll
    for (int j = 0; j < 4; ++j)
        out[(size_t)(bx + ty4 + j) * 1024 + by + tx] = f2bf(tile[tx][ty4 + j]);
}

__global__ __launch_bounds__(256) void pack_bias(const float* __restrict__ bq, const float* __restrict__ bk,
                                                 const float* __restrict__ bv, float* __restrict__ out) {
    int i = blockIdx.x * blockDim.x + threadIdx.x;
    if (i >= 3072) return;
    out[i] = (i < 1024) ? bq[i] : ((i < 2048) ? bk[i - 1024] : bv[i - 2048]);
}

// ---------------- GEMM: C[M x N] = A[M x K] @ Bt[N x K]^T + bias ----------------
template<int MODE>
__global__ __launch_bounds__(256) void gemm128(const u16* __restrict__ A, const u16* __restrict__ Bt,
                                               const float* __restrict__ bias,
                                               u16* __restrict__ oq, u16* __restrict__ ok, u16* __restrict__ ov,
                                               float* __restrict__ of, int K)
{
    __shared__ u16 As[128 * 32];
    __shared__ u16 Bs[128 * 32];

    const int n0 = blockIdx.x * 128;
    const int m0 = blockIdx.y * 128;
    const int t = threadIdx.x;
    const int w = t >> 6, lane = t & 63;
    const int g = lane >> 4, lr = lane & 15;
    const int wm = w >> 1, wn = w & 1;
    const int srow = lane >> 2;
    const int scol = (lane & 3) * 8;

    f32x4 acc[4][4] = {};

    for (int k0 = 0; k0 < K; k0 += 32) {
        __syncthreads();
#pragma unroll
        for (int i = 0; i < 2; ++i) {
            const int c = w + i * 4;
            const int mrow = c * 16 + srow;
            gload16(A  + (size_t)(m0 + mrow) * K + k0 + scol, &As[c * 512 + lane * 8]);
            gload16(Bt + (size_t)(n0 + mrow) * K + k0 + scol, &Bs[c * 512 + lane * 8]);
        }
        __syncthreads();
        bf16x8 af[4], bfr[4];
#pragma unroll
        for (int mi = 0; mi < 4; ++mi) af[mi]  = *(const bf16x8*)&As[(wm * 64 + mi * 16 + lr) * 32 + g * 8];
#pragma unroll
        for (int ni = 0; ni < 4; ++ni) bfr[ni] = *(const bf16x8*)&Bs[(wn * 64 + ni * 16 + lr) * 32 + g * 8];
#pragma unroll
        for (int mi = 0; mi < 4; ++mi)
#pragma unroll
            for (int ni = 0; ni < 4; ++ni)
                acc[mi][ni] = mfma16(af[mi], bfr[ni], acc[mi][ni]);
    }

#pragma unroll
    for (int mi = 0; mi < 4; ++mi) {
#pragma unroll
        for (int ni = 0; ni < 4; ++ni) {
            const int col = n0 + wn * 64 + ni * 16 + lr;
            const int row0 = m0 + wm * 64 + mi * 16 + g * 4;
            const float bs = bias[col];
            if (MODE == 0) {
                const int mat = col >> 10;
                const int nn = col & 1023;
                const int h = nn >> 6, d = nn & 63;
#pragma unroll
                for (int j = 0; j < 4; ++j) {
                    const int rr = row0 + j;
                    const int b = rr >> 11, ll = rr & 2047;
                    const int bh = b * 16 + h;
                    const float v = acc[mi][ni][j] + bs;
                    if (mat == 0)      oq[((size_t)bh * 2048 + ll) * 64 + d] = f2bf(v * 0.125f);
                    else if (mat == 1) ok[((size_t)bh * 2048 + ll) * 64 + d] = f2bf(v);
                    else               ov[((size_t)bh * 64 + d) * 2048 + ll] = f2bf(v);
                }
            } else {
#pragma unroll
                for (int j = 0; j < 4; ++j) {
                    const int rr = row0 + j;
                    of[(size_t)rr * 1024 + col] = acc[mi][ni][j] + bs;
                }
            }
        }
    }
}

// ---------------- flash attention (causal), QBLK=64, 4 waves x 16 q-rows ----------------
// Q,K: [32 bh][2048][64] bf16 (Q pre-scaled by 1/8).  Vt: [32 bh][64][2048] bf16.
// O: [b][l][1024] bf16.
__global__ __launch_bounds__(256) void attn(const u16* __restrict__ Q, const u16* __restrict__ Kg,
                                            const u16* __restrict__ Vt, u16* __restrict__ O)
{
    __shared__ u16 Ks[64 * 64];          // XOR-swizzled 16B chunks
    __shared__ u16 Vs[64 * 64];
    __shared__ u16 Ps[4][16 * 64];       // per-wave P tile, swizzled

    const int bh = blockIdx.x;                       // same-work blocks grouped
    const int qb = (int)gridDim.y - 1 - blockIdx.y;  // heavy q-blocks dispatch first
    const int q0 = qb * 64;
    const int t = threadIdx.x;
    const int w = t >> 6, lane = t & 63;
    const int g = lane >> 4, lr = lane & 15;
    const int qw = q0 + w * 16;
    const int sw = lr & 7;               // swizzle key for fragment reads

    const u16* Qb = Q  + (size_t)bh * 2048 * 64;
    const u16* Kb = Kg + (size_t)bh * 2048 * 64;
    const u16* Vb = Vt + (size_t)bh * 64 * 2048;

    const bf16x8 qf0 = *(const bf16x8*)&Qb[(size_t)(qw + lr) * 64 + g * 8];
    const bf16x8 qf1 = *(const bf16x8*)&Qb[(size_t)(qw + lr) * 64 + 32 + g * 8];

    f32x4 oacc[4] = {};
    float mrun[4], lrun[4];
#pragma unroll
    for (int j = 0; j < 4; ++j) { mrun[j] = -1e30f; lrun[j] = 0.f; }

    for (int kb = 0; kb <= qb; ++kb) {
        const int k0 = kb * 64;
        __syncthreads();
        // stage K [64 k][64 d] and Vt [64 d][64 k] tiles, chunk-XOR swizzled
#pragma unroll
        for (int i = 0; i < 2; ++i) {
            const int c = t + i * 256;           // 0..511
            const int row = c >> 3, ch = c & 7;
            const int chs = ch ^ (row & 7);
            *(bf16x8*)&Ks[row * 64 + chs * 8] = *(const bf16x8*)&Kb[(size_t)(k0 + row) * 64 + ch * 8];
            *(bf16x8*)&Vs[row * 64 + chs * 8] = *(const bf16x8*)&Vb[(size_t)row * 2048 + k0 + ch * 8];
        }
        __syncthreads();

        // S = (Q/8) @ K^T : [16 q x 64 k] per wave
        f32x4 s[4] = {};
        __builtin_amdgcn_s_setprio(1);
#pragma unroll
        for (int ni = 0; ni < 4; ++ni) {
            const int row = ni * 16 + lr;
            bf16x8 kf0 = *(const bf16x8*)&Ks[row * 64 + (g ^ sw) * 8];
            bf16x8 kf1 = *(const bf16x8*)&Ks[row * 64 + ((4 + g) ^ sw) * 8];
            s[ni] = mfma16(qf0, kf0, s[ni]);
            s[ni] = mfma16(qf1, kf1, s[ni]);
        }
        __builtin_amdgcn_s_setprio(0);

        if (kb == qb) {   // only the diagonal tile needs masking
#pragma unroll
            for (int ni = 0; ni < 4; ++ni)
#pragma unroll
                for (int j = 0; j < 4; ++j) {
                    const int kk = k0 + ni * 16 + lr;
                    const int qq = qw + g * 4 + j;
                    if (kk > qq) s[ni][j] = -1e30f;
                }
        }

        // online softmax; rows live on 16-lane groups (g fixed under xor<16)
#pragma unroll
        for (int j = 0; j < 4; ++j) {
            float pm = fmaxf(fmaxf(s[0][j], s[1][j]), fmaxf(s[2][j], s[3][j]));
            pm = fmaxf(pm, __shfl_xor(pm, 1));
            pm = fmaxf(pm, __shfl_xor(pm, 2));
            pm = fmaxf(pm, __shfl_xor(pm, 4));
            pm = fmaxf(pm, __shfl_xor(pm, 8));
            const float mn = fmaxf(mrun[j], pm);
            const float r = __expf(mrun[j] - mn);
            float rs = 0.f;
            const int prow = g * 4 + j;
#pragma unroll
            for (int ni = 0; ni < 4; ++ni) {
                const float p = __expf(s[ni][j] - mn);
                rs += p;
                const int chunk = ni * 2 + (lr >> 3);
                Ps[w][prow * 64 + (chunk ^ (prow & 7)) * 8 + (lr & 7)] = f2bf(p);
            }
            rs += __shfl_xor(rs, 1);
            rs += __shfl_xor(rs, 2);
            rs += __shfl_xor(rs, 4);
            rs += __shfl_xor(rs, 8);
            lrun[j] = lrun[j] * r + rs;
            mrun[j] = mn;
#pragma unroll
            for (int df = 0; df < 4; ++df) oacc[df][j] *= r;
        }
        // P is per-wave private: no barrier needed, only lgkmcnt (compiler-inserted)

        const bf16x8 p0 = *(const bf16x8*)&Ps[w][lr * 64 + (g ^ sw) * 8];
        const bf16x8 p1 = *(const bf16x8*)&Ps[w][lr * 64 + ((4 + g) ^ sw) * 8];
        __builtin_amdgcn_s_setprio(1);
#pragma unroll
        for (int df = 0; df < 4; ++df) {
            const int row = df * 16 + lr;
            bf16x8 vf0 = *(const bf16x8*)&Vs[row * 64 + (g ^ sw) * 8];
            bf16x8 vf1 = *(const bf16x8*)&Vs[row * 64 + ((4 + g) ^ sw) * 8];
            oacc[df] = mfma16(p0, vf0, oacc[df]);
            oacc[df] = mfma16(p1, vf1, oacc[df]);
        }
        __builtin_amdgcn_s_setprio(0);
    }

    // epilogue: normalize, store to [b][l][h*64+d]
    const int b = bh >> 4, h = bh & 15;
#pragma unroll
    for (int j = 0; j < 4; ++j) {
        const float inv = 1.f / lrun[j];
        const int l = qw + g * 4 + j;
#pragma unroll
        for (int df = 0; df < 4; ++df)
            O[((size_t)b * 2048 + l) * 1024 + h * 64 + df * 16 + lr] = f2bf(oacc[df][j] * inv);
    }
}

// ---------------- launch ----------------

extern "C" void kernel_launch(void* const* d_in, const int* in_sizes, int n_in,
                              void* d_out, int out_size, void* d_ws, size_t ws_size,
                              hipStream_t stream)
{
    const float* hs = (const float*)d_in[0];
    const float* Wq = (const float*)d_in[1];
    const float* bq = (const float*)d_in[2];
    const float* Wk = (const float*)d_in[3];
    const float* bk = (const float*)d_in[4];
    const float* Wv = (const float*)d_in[5];
    const float* bv = (const float*)d_in[6];
    const float* Wo = (const float*)d_in[7];
    const float* bo = (const float*)d_in[8];
    float* out = (float*)d_out;

    char* ws = (char*)d_ws;
    u16*   Xbf   = (u16*)(ws);                     // 8 MB, reused as Abuf after QKV GEMM
    u16*   Wqkvt = (u16*)(ws + (8ull  << 20));     // 6 MB
    u16*   Wot   = (u16*)(ws + (14ull << 20));     // 2 MB
    float* bqkv  = (float*)(ws + (16ull << 20));   // 12 KB
    u16*   Qbuf  = (u16*)(ws + (17ull << 20));     // 8 MB
    u16*   Kbuf  = (u16*)(ws + (25ull << 20));     // 8 MB
    u16*   Vtbuf = (u16*)(ws + (33ull << 20));     // 8 MB
    u16*   Abuf  = Xbf;                            // alias: X dead after QKV GEMM

    cvt_x<<<4096, 256, 0, stream>>>(hs, Xbf, 4096 * 1024 / 4);
    transpose_w<<<dim3(32, 32), 256, 0, stream>>>(Wq, Wqkvt);
    transpose_w<<<dim3(32, 32), 256, 0, stream>>>(Wk, Wqkvt + 1024 * 1024);
    transpose_w<<<dim3(32, 32), 256, 0, stream>>>(Wv, Wqkvt + 2 * 1024 * 1024);
    transpose_w<<<dim3(32, 32), 256, 0, stream>>>(Wo, Wot);
    pack_bias<<<12, 256, 0, stream>>>(bq, bk, bv, bqkv);

    // QKV: [4096 x 3072]
    gemm128<0><<<dim3(24, 32), 256, 0, stream>>>(Xbf, Wqkvt, bqkv, Qbuf, Kbuf, Vtbuf, nullptr, 1024);
    // attention: grid (bh, qb), QBLK=64
    attn<<<dim3(32, 32), 256, 0, stream>>>(Qbuf, Kbuf, Vtbuf, Abuf);
    // output projection: [4096 x 1024] -> fp32 d_out
    gemm128<1><<<dim3(8, 32), 256, 0, stream>>>(Abuf, Wot, bo, nullptr, nullptr, nullptr, out, 1024);
}

// Round 3
// 152.281 us; speedup vs baseline: 1.3685x; 1.0155x over previous
//
#include <hip/hip_runtime.h>

typedef unsigned short u16;
typedef unsigned int u32;
typedef __attribute__((ext_vector_type(8))) short bf16x8;
typedef __attribute__((ext_vector_type(4))) float f32x4;

__device__ __forceinline__ u16 f2bf(float f) {          // full RNE (cold paths)
    union { float f; u32 u; } x; x.f = f;
    u32 r = x.u + 0x7FFFu + ((x.u >> 16) & 1u);
    return (u16)(r >> 16);
}

__device__ __forceinline__ u16 f2bf_fast(float f) {     // round-half-up (hot path)
    union { float f; u32 u; } x; x.f = f;
    return (u16)((x.u + 0x8000u) >> 16);
}

__device__ __forceinline__ void gload16(const u16* g, u16* l) {
    __builtin_amdgcn_global_load_lds(
        (const __attribute__((address_space(1))) void*)g,
        (__attribute__((address_space(3))) void*)l,
        16, 0, 0);
}

__device__ __forceinline__ f32x4 mfma16(bf16x8 a, bf16x8 b, f32x4 c) {
    return __builtin_amdgcn_mfma_f32_16x16x32_bf16(a, b, c, 0, 0, 0);
}

// ---------------- prep kernels ----------------

__global__ __launch_bounds__(256) void cvt_x(const float* __restrict__ in, u16* __restrict__ out, int n4) {
    int i = blockIdx.x * blockDim.x + threadIdx.x;
    if (i >= n4) return;
    float4 v = ((const float4*)in)[i];
    u16* o = out + (size_t)i * 4;
    o[0] = f2bf(v.x); o[1] = f2bf(v.y); o[2] = f2bf(v.z); o[3] = f2bf(v.w);
}

// all 4 weights in one launch; z selects the matrix
__global__ __launch_bounds__(256) void transpose_w4(const float* __restrict__ Wq, const float* __restrict__ Wk,
                                                    const float* __restrict__ Wv, const float* __restrict__ Wo,
                                                    u16* __restrict__ qkvt, u16* __restrict__ wot) {
    __shared__ float tile[32][33];
    const float* in;
    u16* out;
    if (blockIdx.z == 0)      { in = Wq; out = qkvt; }
    else if (blockIdx.z == 1) { in = Wk; out = qkvt + 1024 * 1024; }
    else if (blockIdx.z == 2) { in = Wv; out = qkvt + 2 * 1024 * 1024; }
    else                      { in = Wo; out = wot; }
    const int bx = blockIdx.x * 32, by = blockIdx.y * 32;
    const int tx = threadIdx.x & 31, ty4 = (threadIdx.x >> 5) * 4;
#pragma unroll
    for (int j = 0; j < 4; ++j)
        tile[ty4 + j][tx] = in[(size_t)(by + ty4 + j) * 1024 + bx + tx];
    __syncthreads();
#pragma unroll
    for (int j = 0; j < 4; ++j)
        out[(size_t)(bx + ty4 + j) * 1024 + by + tx] = f2bf(tile[tx][ty4 + j]);
}

__global__ __launch_bounds__(256) void pack_bias(const float* __restrict__ bq, const float* __restrict__ bk,
                                                 const float* __restrict__ bv, float* __restrict__ out) {
    int i = blockIdx.x * blockDim.x + threadIdx.x;
    if (i >= 3072) return;
    out[i] = (i < 1024) ? bq[i] : ((i < 2048) ? bk[i - 1024] : bv[i - 2048]);
}

// ---------------- GEMM: C[M x N] = A[M x K] @ Bt[N x K]^T + bias ----------------
template<int MODE>
__global__ __launch_bounds__(256) void gemm128(const u16* __restrict__ A, const u16* __restrict__ Bt,
                                               const float* __restrict__ bias,
                                               u16* __restrict__ oq, u16* __restrict__ ok, u16* __restrict__ ov,
                                               float* __restrict__ of, int K)
{
    __shared__ u16 As[128 * 32];
    __shared__ u16 Bs[128 * 32];

    const int n0 = blockIdx.x * 128;
    const int m0 = blockIdx.y * 128;
    const int t = threadIdx.x;
    const int w = t >> 6, lane = t & 63;
    const int g = lane >> 4, lr = lane & 15;
    const int wm = w >> 1, wn = w & 1;
    const int srow = lane >> 2;
    const int scol = (lane & 3) * 8;

    f32x4 acc[4][4] = {};

    for (int k0 = 0; k0 < K; k0 += 32) {
        __syncthreads();
#pragma unroll
        for (int i = 0; i < 2; ++i) {
            const int c = w + i * 4;
            const int mrow = c * 16 + srow;
            gload16(A  + (size_t)(m0 + mrow) * K + k0 + scol, &As[c * 512 + lane * 8]);
            gload16(Bt + (size_t)(n0 + mrow) * K + k0 + scol, &Bs[c * 512 + lane * 8]);
        }
        __syncthreads();
        bf16x8 af[4], bfr[4];
#pragma unroll
        for (int mi = 0; mi < 4; ++mi) af[mi]  = *(const bf16x8*)&As[(wm * 64 + mi * 16 + lr) * 32 + g * 8];
#pragma unroll
        for (int ni = 0; ni < 4; ++ni) bfr[ni] = *(const bf16x8*)&Bs[(wn * 64 + ni * 16 + lr) * 32 + g * 8];
#pragma unroll
        for (int mi = 0; mi < 4; ++mi)
#pragma unroll
            for (int ni = 0; ni < 4; ++ni)
                acc[mi][ni] = mfma16(af[mi], bfr[ni], acc[mi][ni]);
    }

#pragma unroll
    for (int mi = 0; mi < 4; ++mi) {
#pragma unroll
        for (int ni = 0; ni < 4; ++ni) {
            const int col = n0 + wn * 64 + ni * 16 + lr;
            const int row0 = m0 + wm * 64 + mi * 16 + g * 4;
            const float bs = bias[col];
            if (MODE == 0) {
                const int mat = col >> 10;
                const int nn = col & 1023;
                const int h = nn >> 6, d = nn & 63;
#pragma unroll
                for (int j = 0; j < 4; ++j) {
                    const int rr = row0 + j;
                    const int b = rr >> 11, ll = rr & 2047;
                    const int bh = b * 16 + h;
                    const float v = acc[mi][ni][j] + bs;
                    // Q pre-scaled by (1/8)*log2(e) so softmax runs in exp2 domain
                    if (mat == 0)      oq[((size_t)bh * 2048 + ll) * 64 + d] = f2bf(v * 0.1803368801111244f);
                    else if (mat == 1) ok[((size_t)bh * 2048 + ll) * 64 + d] = f2bf(v);
                    else               ov[((size_t)bh * 64 + d) * 2048 + ll] = f2bf(v);
                }
            } else {
#pragma unroll
                for (int j = 0; j < 4; ++j) {
                    const int rr = row0 + j;
                    of[(size_t)rr * 1024 + col] = acc[mi][ni][j] + bs;
                }
            }
        }
    }
}

// ---------------- flash attention (causal), paired q-tiles, dbuf K/V, exp2 softmax ----------------
// Q,K: [32 bh][2048][64] bf16 (Q pre-scaled by log2e/8).  Vt: [32 bh][64][2048] bf16.
// O: [b][l][1024] bf16.  Block (bh, p) owns q-tiles qa=p (light) and qb2=31-p (heavy);
// one shared k-loop stages K/V once; per-block MFMA work is uniform (33 tile-visits).
__global__ __launch_bounds__(256) void attn(const u16* __restrict__ Q, const u16* __restrict__ Kg,
                                            const u16* __restrict__ Vt, u16* __restrict__ O)
{
    __shared__ u16 Ks[2][64 * 64];
    __shared__ u16 Vs[2][64 * 64];
    __shared__ u16 Ps[4][16 * 64];

    const int bh = blockIdx.x;
    const int p  = blockIdx.y;             // 0..15
    const int qa = p, qb2 = 31 - p;
    const int t = threadIdx.x;
    const int w = t >> 6, lane = t & 63;
    const int g = lane >> 4, lr = lane & 15;
    const int sw = lr & 7;

    const u16* Qb = Q  + (size_t)bh * 2048 * 64;
    const u16* Kb = Kg + (size_t)bh * 2048 * 64;
    const u16* Vb = Vt + (size_t)bh * 64 * 2048;

    const int rA = qa * 64 + w * 16;       // wave's first q-row, segment A
    const int rB = qb2 * 64 + w * 16;      // segment B

    const bf16x8 qA0 = *(const bf16x8*)&Qb[(size_t)(rA + lr) * 64 + g * 8];
    const bf16x8 qA1 = *(const bf16x8*)&Qb[(size_t)(rA + lr) * 64 + 32 + g * 8];
    const bf16x8 qB0 = *(const bf16x8*)&Qb[(size_t)(rB + lr) * 64 + g * 8];
    const bf16x8 qB1 = *(const bf16x8*)&Qb[(size_t)(rB + lr) * 64 + 32 + g * 8];

    f32x4 oA[4] = {}, oB[4] = {};
    float mA[4], lA[4], mB[4], lB[4];
#pragma unroll
    for (int j = 0; j < 4; ++j) { mA[j] = mB[j] = -1e30f; lA[j] = lB[j] = 0.f; }

    // reg staging (T14 issue-early / commit-late), double-buffered LDS
    bf16x8 kreg[2], vreg[2];
    const int srow0 = t >> 3, sch = t & 7;     // chunk 0: rows 0..31; chunk 1: rows 32..63
    auto issue = [&](int kb) {
#pragma unroll
        for (int i = 0; i < 2; ++i) {
            const int row = srow0 + i * 32;
            kreg[i] = *(const bf16x8*)&Kb[(size_t)(kb * 64 + row) * 64 + sch * 8];
            vreg[i] = *(const bf16x8*)&Vb[(size_t)row * 2048 + kb * 64 + sch * 8];
        }
    };
    auto commit = [&](int buf) {
#pragma unroll
        for (int i = 0; i < 2; ++i) {
            const int row = srow0 + i * 32;
            const int chs = sch ^ (row & 7);
            *(bf16x8*)&Ks[buf][row * 64 + chs * 8] = kreg[i];
            *(bf16x8*)&Vs[buf][row * 64 + chs * 8] = vreg[i];
        }
    };

    auto qk_sm = [&](const bf16x8& qf0, const bf16x8& qf1, f32x4 (&oacc)[4],
                     float (&mrun)[4], float (&lrun)[4], int qrow0, int k0,
                     const u16* ks, bool diag) {
        f32x4 s[4] = {};
        __builtin_amdgcn_s_setprio(1);
#pragma unroll
        for (int ni = 0; ni < 4; ++ni) {
            const int row = ni * 16 + lr;
            bf16x8 kf0 = *(const bf16x8*)&ks[row * 64 + (g ^ sw) * 8];
            bf16x8 kf1 = *(const bf16x8*)&ks[row * 64 + ((4 + g) ^ sw) * 8];
            s[ni] = mfma16(qf0, kf0, s[ni]);
            s[ni] = mfma16(qf1, kf1, s[ni]);
        }
        __builtin_amdgcn_s_setprio(0);
        if (diag) {
#pragma unroll
            for (int ni = 0; ni < 4; ++ni)
#pragma unroll
                for (int j = 0; j < 4; ++j)
                    if (k0 + ni * 16 + lr > qrow0 + g * 4 + j) s[ni][j] = -1e30f;
        }
        float pm[4];
#pragma unroll
        for (int j = 0; j < 4; ++j) {
            float m0 = fmaxf(fmaxf(s[0][j], s[1][j]), fmaxf(s[2][j], s[3][j]));
            m0 = fmaxf(m0, __shfl_xor(m0, 1));
            m0 = fmaxf(m0, __shfl_xor(m0, 2));
            m0 = fmaxf(m0, __shfl_xor(m0, 4));
            m0 = fmaxf(m0, __shfl_xor(m0, 8));
            pm[j] = m0;
        }
        // defer-max (T13): only rescale when some row grew past THR=8 (exp2 domain; P <= 256)
        const bool need = (pm[0] > mrun[0] + 8.f) || (pm[1] > mrun[1] + 8.f) ||
                          (pm[2] > mrun[2] + 8.f) || (pm[3] > mrun[3] + 8.f);
        if (__any(need)) {
#pragma unroll
            for (int j = 0; j < 4; ++j) {
                const float mn = fmaxf(mrun[j], pm[j]);
                const float r = __builtin_amdgcn_exp2f(mrun[j] - mn);
                mrun[j] = mn;
                lrun[j] *= r;
#pragma unroll
                for (int df = 0; df < 4; ++df) oacc[df][j] *= r;
            }
        }
#pragma unroll
        for (int j = 0; j < 4; ++j) {
            const int prow = g * 4 + j;
            float rs = 0.f;
#pragma unroll
            for (int ni = 0; ni < 4; ++ni) {
                const float pv = __builtin_amdgcn_exp2f(s[ni][j] - mrun[j]);
                rs += pv;
                const int chunk = ni * 2 + (lr >> 3);
                Ps[w][prow * 64 + (chunk ^ (prow & 7)) * 8 + (lr & 7)] = f2bf_fast(pv);
            }
            rs += __shfl_xor(rs, 1);
            rs += __shfl_xor(rs, 2);
            rs += __shfl_xor(rs, 4);
            rs += __shfl_xor(rs, 8);
            lrun[j] += rs;
        }
    };

    auto pv = [&](f32x4 (&oacc)[4], const u16* vs) {
        const bf16x8 p0 = *(const bf16x8*)&Ps[w][lr * 64 + (g ^ sw) * 8];
        const bf16x8 p1 = *(const bf16x8*)&Ps[w][lr * 64 + ((4 + g) ^ sw) * 8];
        __builtin_amdgcn_s_setprio(1);
#pragma unroll
        for (int df = 0; df < 4; ++df) {
            const int row = df * 16 + lr;
            bf16x8 vf0 = *(const bf16x8*)&vs[row * 64 + (g ^ sw) * 8];
            bf16x8 vf1 = *(const bf16x8*)&vs[row * 64 + ((4 + g) ^ sw) * 8];
            oacc[df] = mfma16(p0, vf0, oacc[df]);
            oacc[df] = mfma16(p1, vf1, oacc[df]);
        }
        __builtin_amdgcn_s_setprio(0);
    };

    issue(0);
    commit(0);

    for (int kb = 0; kb <= qb2; ++kb) {
        const int cur = kb & 1;
        const int k0 = kb * 64;
        __syncthreads();                       // publishes LDS[cur]
        const bool more = (kb < qb2);
        if (more) issue(kb + 1);               // loads fly under QK+softmax

        qk_sm(qB0, qB1, oB, mB, lB, rB, k0, Ks[cur], kb == qb2);
        if (more) commit(cur ^ 1);             // waits vmcnt on kreg/vreg only
        pv(oB, Vs[cur]);

        if (kb <= qa) {
            qk_sm(qA0, qA1, oA, mA, lA, rA, k0, Ks[cur], kb == qa);
            pv(oA, Vs[cur]);
        }
    }

    // epilogue: normalize, store both segments to [b][l][h*64+d]
    const int b = bh >> 4, h = bh & 15;
#pragma unroll
    for (int j = 0; j < 4; ++j) {
        const float invA = 1.f / lA[j];
        const float invB = 1.f / lB[j];
        const int la = rA + g * 4 + j;
        const int lb = rB + g * 4 + j;
#pragma unroll
        for (int df = 0; df < 4; ++df) {
            O[((size_t)b * 2048 + la) * 1024 + h * 64 + df * 16 + lr] = f2bf(oA[df][j] * invA);
            O[((size_t)b * 2048 + lb) * 1024 + h * 64 + df * 16 + lr] = f2bf(oB[df][j] * invB);
        }
    }
}

// ---------------- launch ----------------

extern "C" void kernel_launch(void* const* d_in, const int* in_sizes, int n_in,
                              void* d_out, int out_size, void* d_ws, size_t ws_size,
                              hipStream_t stream)
{
    const float* hs = (const float*)d_in[0];
    const float* Wq = (const float*)d_in[1];
    const float* bq = (const float*)d_in[2];
    const float* Wk = (const float*)d_in[3];
    const float* bk = (const float*)d_in[4];
    const float* Wv = (const float*)d_in[5];
    const float* bv = (const float*)d_in[6];
    const float* Wo = (const float*)d_in[7];
    const float* bo = (const float*)d_in[8];
    float* out = (float*)d_out;

    char* ws = (char*)d_ws;
    u16*   Xbf   = (u16*)(ws);                     // 8 MB, reused as Abuf after QKV GEMM
    u16*   Wqkvt = (u16*)(ws + (8ull  << 20));     // 6 MB
    u16*   Wot   = (u16*)(ws + (14ull << 20));     // 2 MB
    float* bqkv  = (float*)(ws + (16ull << 20));   // 12 KB
    u16*   Qbuf  = (u16*)(ws + (17ull << 20));     // 8 MB
    u16*   Kbuf  = (u16*)(ws + (25ull << 20));     // 8 MB
    u16*   Vtbuf = (u16*)(ws + (33ull << 20));     // 8 MB
    u16*   Abuf  = Xbf;                            // alias: X dead after QKV GEMM

    cvt_x<<<4096, 256, 0, stream>>>(hs, Xbf, 4096 * 1024 / 4);
    transpose_w4<<<dim3(32, 32, 4), 256, 0, stream>>>(Wq, Wk, Wv, Wo, Wqkvt, Wot);
    pack_bias<<<12, 256, 0, stream>>>(bq, bk, bv, bqkv);

    // QKV: [4096 x 3072]
    gemm128<0><<<dim3(24, 32), 256, 0, stream>>>(Xbf, Wqkvt, bqkv, Qbuf, Kbuf, Vtbuf, nullptr, 1024);
    // attention: grid (bh, pair), uniform work per block
    attn<<<dim3(32, 16), 256, 0, stream>>>(Qbuf, Kbuf, Vtbuf, Abuf);
    // output projection: [4096 x 1024] -> fp32 d_out
    gemm128<1><<<dim3(8, 32), 256, 0, stream>>>(Abuf, Wot, bo, nullptr, nullptr, nullptr, out, 1024);
}

// Round 4
// 143.857 us; speedup vs baseline: 1.4486x; 1.0586x over previous
//
#include <hip/hip_runtime.h>

typedef unsigned short u16;
typedef unsigned int u32;
typedef __attribute__((ext_vector_type(8))) short bf16x8;
typedef __attribute__((ext_vector_type(4))) float f32x4;

__device__ __forceinline__ u16 f2bf(float f) {          // full RNE (cold paths)
    union { float f; u32 u; } x; x.f = f;
    u32 r = x.u + 0x7FFFu + ((x.u >> 16) & 1u);
    return (u16)(r >> 16);
}

__device__ __forceinline__ u16 f2bf_fast(float f) {     // round-half-up (hot path)
    union { float f; u32 u; } x; x.f = f;
    return (u16)((x.u + 0x8000u) >> 16);
}

__device__ __forceinline__ void gload16(const u16* g, u16* l) {
    __builtin_amdgcn_global_load_lds(
        (const __attribute__((address_space(1))) void*)g,
        (__attribute__((address_space(3))) void*)l,
        16, 0, 0);
}

__device__ __forceinline__ f32x4 mfma16(bf16x8 a, bf16x8 b, f32x4 c) {
    return __builtin_amdgcn_mfma_f32_16x16x32_bf16(a, b, c, 0, 0, 0);
}

// ---------------- prep kernels ----------------

__global__ __launch_bounds__(256) void cvt_x(const float* __restrict__ in, u16* __restrict__ out, int n4) {
    int i = blockIdx.x * blockDim.x + threadIdx.x;
    if (i >= n4) return;
    float4 v = ((const float4*)in)[i];
    u16* o = out + (size_t)i * 4;
    o[0] = f2bf(v.x); o[1] = f2bf(v.y); o[2] = f2bf(v.z); o[3] = f2bf(v.w);
}

// all 4 weights in one launch; z selects the matrix
__global__ __launch_bounds__(256) void transpose_w4(const float* __restrict__ Wq, const float* __restrict__ Wk,
                                                    const float* __restrict__ Wv, const float* __restrict__ Wo,
                                                    u16* __restrict__ qkvt, u16* __restrict__ wot) {
    __shared__ float tile[32][33];
    const float* in;
    u16* out;
    if (blockIdx.z == 0)      { in = Wq; out = qkvt; }
    else if (blockIdx.z == 1) { in = Wk; out = qkvt + 1024 * 1024; }
    else if (blockIdx.z == 2) { in = Wv; out = qkvt + 2 * 1024 * 1024; }
    else                      { in = Wo; out = wot; }
    const int bx = blockIdx.x * 32, by = blockIdx.y * 32;
    const int tx = threadIdx.x & 31, ty4 = (threadIdx.x >> 5) * 4;
#pragma unroll
    for (int j = 0; j < 4; ++j)
        tile[ty4 + j][tx] = in[(size_t)(by + ty4 + j) * 1024 + bx + tx];
    __syncthreads();
#pragma unroll
    for (int j = 0; j < 4; ++j)
        out[(size_t)(bx + ty4 + j) * 1024 + by + tx] = f2bf(tile[tx][ty4 + j]);
}

__global__ __launch_bounds__(256) void pack_bias(const float* __restrict__ bq, const float* __restrict__ bk,
                                                 const float* __restrict__ bv, float* __restrict__ out) {
    int i = blockIdx.x * blockDim.x + threadIdx.x;
    if (i >= 3072) return;
    out[i] = (i < 1024) ? bq[i] : ((i < 2048) ? bk[i - 1024] : bv[i - 2048]);
}

// ---------------- GEMM: C[M x N] = A[M x K] @ Bt[N x K]^T + bias ----------------
template<int MODE>
__global__ __launch_bounds__(256) void gemm128(const u16* __restrict__ A, const u16* __restrict__ Bt,
                                               const float* __restrict__ bias,
                                               u16* __restrict__ oq, u16* __restrict__ ok, u16* __restrict__ ov,
                                               float* __restrict__ of, int K)
{
    __shared__ u16 As[128 * 32];
    __shared__ u16 Bs[128 * 32];

    const int n0 = blockIdx.x * 128;
    const int m0 = blockIdx.y * 128;
    const int t = threadIdx.x;
    const int w = t >> 6, lane = t & 63;
    const int g = lane >> 4, lr = lane & 15;
    const int wm = w >> 1, wn = w & 1;
    const int srow = lane >> 2;
    const int scol = (lane & 3) * 8;

    f32x4 acc[4][4] = {};

    for (int k0 = 0; k0 < K; k0 += 32) {
        __syncthreads();
#pragma unroll
        for (int i = 0; i < 2; ++i) {
            const int c = w + i * 4;
            const int mrow = c * 16 + srow;
            gload16(A  + (size_t)(m0 + mrow) * K + k0 + scol, &As[c * 512 + lane * 8]);
            gload16(Bt + (size_t)(n0 + mrow) * K + k0 + scol, &Bs[c * 512 + lane * 8]);
        }
        __syncthreads();
        bf16x8 af[4], bfr[4];
#pragma unroll
        for (int mi = 0; mi < 4; ++mi) af[mi]  = *(const bf16x8*)&As[(wm * 64 + mi * 16 + lr) * 32 + g * 8];
#pragma unroll
        for (int ni = 0; ni < 4; ++ni) bfr[ni] = *(const bf16x8*)&Bs[(wn * 64 + ni * 16 + lr) * 32 + g * 8];
#pragma unroll
        for (int mi = 0; mi < 4; ++mi)
#pragma unroll
            for (int ni = 0; ni < 4; ++ni)
                acc[mi][ni] = mfma16(af[mi], bfr[ni], acc[mi][ni]);
    }

#pragma unroll
    for (int mi = 0; mi < 4; ++mi) {
#pragma unroll
        for (int ni = 0; ni < 4; ++ni) {
            const int col = n0 + wn * 64 + ni * 16 + lr;
            const int row0 = m0 + wm * 64 + mi * 16 + g * 4;
            const float bs = bias[col];
            if (MODE == 0) {
                const int mat = col >> 10;
                const int nn = col & 1023;
                const int h = nn >> 6, d = nn & 63;
#pragma unroll
                for (int j = 0; j < 4; ++j) {
                    const int rr = row0 + j;
                    const int b = rr >> 11, ll = rr & 2047;
                    const int bh = b * 16 + h;
                    const float v = acc[mi][ni][j] + bs;
                    // Q pre-scaled by (1/8)*log2(e) so softmax runs in exp2 domain
                    if (mat == 0)      oq[((size_t)bh * 2048 + ll) * 64 + d] = f2bf(v * 0.1803368801111244f);
                    else if (mat == 1) ok[((size_t)bh * 2048 + ll) * 64 + d] = f2bf(v);
                    else               ov[((size_t)bh * 64 + d) * 2048 + ll] = f2bf(v);
                }
            } else {
#pragma unroll
                for (int j = 0; j < 4; ++j) {
                    const int rr = row0 + j;
                    of[(size_t)rr * 1024 + col] = acc[mi][ni][j] + bs;
                }
            }
        }
    }
}

// ---------------- flash attention (causal), QBLK=64, dbuf K/V, ones-MFMA row-sum ----------------
// Q,K: [32 bh][2048][64] bf16 (Q pre-scaled by log2e/8).  Vt: [32 bh][64][2048] bf16.
// O: [b][l][1024] bf16.
__global__ __launch_bounds__(256) void attn(const u16* __restrict__ Q, const u16* __restrict__ Kg,
                                            const u16* __restrict__ Vt, u16* __restrict__ O)
{
    __shared__ u16 Ks[2][64 * 64];
    __shared__ u16 Vs[2][64 * 64];
    __shared__ u16 Ps[4][16 * 64];

    const int bh = blockIdx.x;                       // fastest-varying: all bh of a qb dispatch together
    const int qb = (int)gridDim.y - 1 - blockIdx.y;  // heavy q-blocks dispatch first
    const int q0 = qb * 64;
    const int t = threadIdx.x;
    const int w = t >> 6, lane = t & 63;
    const int g = lane >> 4, lr = lane & 15;
    const int qw = q0 + w * 16;
    const int sw = lr & 7;

    const u16* Qb = Q  + (size_t)bh * 2048 * 64;
    const u16* Kb = Kg + (size_t)bh * 2048 * 64;
    const u16* Vb = Vt + (size_t)bh * 64 * 2048;

    const bf16x8 qf0 = *(const bf16x8*)&Qb[(size_t)(qw + lr) * 64 + g * 8];
    const bf16x8 qf1 = *(const bf16x8*)&Qb[(size_t)(qw + lr) * 64 + 32 + g * 8];

    const short one = (short)0x3F80;                 // bf16 1.0
    const bf16x8 vones = {one, one, one, one, one, one, one, one};

    f32x4 oacc[4] = {};
    f32x4 lsacc = {};                                // row-sum accumulator (P @ ones), same row layout as oacc
    float mrun[4];
#pragma unroll
    for (int j = 0; j < 4; ++j) mrun[j] = -1e30f;

    // T14 reg staging, double-buffered LDS, 1 barrier per tile
    bf16x8 kreg[2], vreg[2];
    const int srow0 = t >> 3, sch = t & 7;
    auto issue = [&](int kb) {
#pragma unroll
        for (int i = 0; i < 2; ++i) {
            const int row = srow0 + i * 32;
            kreg[i] = *(const bf16x8*)&Kb[(size_t)(kb * 64 + row) * 64 + sch * 8];
            vreg[i] = *(const bf16x8*)&Vb[(size_t)row * 2048 + kb * 64 + sch * 8];
        }
    };
    auto commit = [&](int buf) {
#pragma unroll
        for (int i = 0; i < 2; ++i) {
            const int row = srow0 + i * 32;
            const int chs = sch ^ (row & 7);
            *(bf16x8*)&Ks[buf][row * 64 + chs * 8] = kreg[i];
            *(bf16x8*)&Vs[buf][row * 64 + chs * 8] = vreg[i];
        }
    };

    issue(0);
    commit(0);

    for (int kb = 0; kb <= qb; ++kb) {
        const int cur = kb & 1;
        const int k0 = kb * 64;
        __syncthreads();                     // publishes LDS[cur] (all waves' commits)
        const bool more = (kb < qb);
        if (more) issue(kb + 1);             // global loads fly under QK + softmax

        // ---- S = (Q*log2e/8) @ K^T : [16 q x 64 k] per wave ----
        f32x4 s[4] = {};
        __builtin_amdgcn_s_setprio(1);
#pragma unroll
        for (int ni = 0; ni < 4; ++ni) {
            const int row = ni * 16 + lr;
            bf16x8 kf0 = *(const bf16x8*)&Ks[cur][row * 64 + (g ^ sw) * 8];
            bf16x8 kf1 = *(const bf16x8*)&Ks[cur][row * 64 + ((4 + g) ^ sw) * 8];
            s[ni] = mfma16(qf0, kf0, s[ni]);
            s[ni] = mfma16(qf1, kf1, s[ni]);
        }
        __builtin_amdgcn_s_setprio(0);

        if (kb == qb) {                      // diagonal tile: causal mask
#pragma unroll
            for (int ni = 0; ni < 4; ++ni)
#pragma unroll
                for (int j = 0; j < 4; ++j)
                    if (k0 + ni * 16 + lr > qw + g * 4 + j) s[ni][j] = -1e30f;
        }

        // ---- online softmax: max via shfl butterfly; sum via ones-MFMA (below) ----
        float pm[4];
#pragma unroll
        for (int j = 0; j < 4; ++j) {
            float m0 = fmaxf(fmaxf(s[0][j], s[1][j]), fmaxf(s[2][j], s[3][j]));
            m0 = fmaxf(m0, __shfl_xor(m0, 1));
            m0 = fmaxf(m0, __shfl_xor(m0, 2));
            m0 = fmaxf(m0, __shfl_xor(m0, 4));
            m0 = fmaxf(m0, __shfl_xor(m0, 8));
            pm[j] = m0;
        }
        // defer-max (T13, THR=8 in exp2 domain => P <= 256)
        const bool need = (pm[0] > mrun[0] + 8.f) || (pm[1] > mrun[1] + 8.f) ||
                          (pm[2] > mrun[2] + 8.f) || (pm[3] > mrun[3] + 8.f);
        if (__any(need)) {
#pragma unroll
            for (int j = 0; j < 4; ++j) {
                const float mn = fmaxf(mrun[j], pm[j]);
                const float r = __builtin_amdgcn_exp2f(mrun[j] - mn);
                mrun[j] = mn;
                lsacc[j] *= r;
#pragma unroll
                for (int df = 0; df < 4; ++df) oacc[df][j] *= r;
            }
        }
#pragma unroll
        for (int j = 0; j < 4; ++j) {
            const int prow = g * 4 + j;
#pragma unroll
            for (int ni = 0; ni < 4; ++ni) {
                const float pv = __builtin_amdgcn_exp2f(s[ni][j] - mrun[j]);
                const int chunk = ni * 2 + (lr >> 3);
                Ps[w][prow * 64 + (chunk ^ (prow & 7)) * 8 + (lr & 7)] = f2bf_fast(pv);
            }
        }
        // P is per-wave private: lgkmcnt (compiler) orders write->read, no barrier

        if (more) commit(cur ^ 1);           // vmcnt wait on kreg/vreg, write other buffer

        // ---- O += P @ V ; l += P @ 1 (row-sum on the matrix pipe) ----
        const bf16x8 p0 = *(const bf16x8*)&Ps[w][lr * 64 + (g ^ sw) * 8];
        const bf16x8 p1 = *(const bf16x8*)&Ps[w][lr * 64 + ((4 + g) ^ sw) * 8];
        __builtin_amdgcn_s_setprio(1);
        lsacc = mfma16(p0, vones, lsacc);
        lsacc = mfma16(p1, vones, lsacc);
#pragma unroll
        for (int df = 0; df < 4; ++df) {
            const int row = df * 16 + lr;
            bf16x8 vf0 = *(const bf16x8*)&Vs[cur][row * 64 + (g ^ sw) * 8];
            bf16x8 vf1 = *(const bf16x8*)&Vs[cur][row * 64 + ((4 + g) ^ sw) * 8];
            oacc[df] = mfma16(p0, vf0, oacc[df]);
            oacc[df] = mfma16(p1, vf1, oacc[df]);
        }
        __builtin_amdgcn_s_setprio(0);
    }

    // epilogue: normalize by the MFMA-accumulated row sums; store to [b][l][h*64+d]
    const int b = bh >> 4, h = bh & 15;
#pragma unroll
    for (int j = 0; j < 4; ++j) {
        const float inv = 1.f / lsacc[j];
        const int l = qw + g * 4 + j;
#pragma unroll
        for (int df = 0; df < 4; ++df)
            O[((size_t)b * 2048 + l) * 1024 + h * 64 + df * 16 + lr] = f2bf(oacc[df][j] * inv);
    }
}

// ---------------- launch ----------------

extern "C" void kernel_launch(void* const* d_in, const int* in_sizes, int n_in,
                              void* d_out, int out_size, void* d_ws, size_t ws_size,
                              hipStream_t stream)
{
    const float* hs = (const float*)d_in[0];
    const float* Wq = (const float*)d_in[1];
    const float* bq = (const float*)d_in[2];
    const float* Wk = (const float*)d_in[3];
    const float* bk = (const float*)d_in[4];
    const float* Wv = (const float*)d_in[5];
    const float* bv = (const float*)d_in[6];
    const float* Wo = (const float*)d_in[7];
    const float* bo = (const float*)d_in[8];
    float* out = (float*)d_out;

    char* ws = (char*)d_ws;
    u16*   Xbf   = (u16*)(ws);                     // 8 MB, reused as Abuf after QKV GEMM
    u16*   Wqkvt = (u16*)(ws + (8ull  << 20));     // 6 MB
    u16*   Wot   = (u16*)(ws + (14ull << 20));     // 2 MB
    float* bqkv  = (float*)(ws + (16ull << 20));   // 12 KB
    u16*   Qbuf  = (u16*)(ws + (17ull << 20));     // 8 MB
    u16*   Kbuf  = (u16*)(ws + (25ull << 20));     // 8 MB
    u16*   Vtbuf = (u16*)(ws + (33ull << 20));     // 8 MB
    u16*   Abuf  = Xbf;                            // alias: X dead after QKV GEMM

    cvt_x<<<4096, 256, 0, stream>>>(hs, Xbf, 4096 * 1024 / 4);
    transpose_w4<<<dim3(32, 32, 4), 256, 0, stream>>>(Wq, Wk, Wv, Wo, Wqkvt, Wot);
    pack_bias<<<12, 256, 0, stream>>>(bq, bk, bv, bqkv);

    // QKV: [4096 x 3072]
    gemm128<0><<<dim3(24, 32), 256, 0, stream>>>(Xbf, Wqkvt, bqkv, Qbuf, Kbuf, Vtbuf, nullptr, 1024);
    // attention: grid (bh, qb), QBLK=64, heavy-first
    attn<<<dim3(32, 32), 256, 0, stream>>>(Qbuf, Kbuf, Vtbuf, Abuf);
    // output projection: [4096 x 1024] -> fp32 d_out
    gemm128<1><<<dim3(8, 32), 256, 0, stream>>>(Abuf, Wot, bo, nullptr, nullptr, nullptr, out, 1024);
}

// Round 7
// 134.851 us; speedup vs baseline: 1.5454x; 1.0668x over previous
//
#include <hip/hip_runtime.h>

typedef unsigned short u16;
typedef unsigned int u32;
typedef __attribute__((ext_vector_type(8))) short bf16x8;
typedef __attribute__((ext_vector_type(4))) float f32x4;

__device__ __forceinline__ u16 f2bf(float f) {          // full RNE
    union { float f; u32 u; } x; x.f = f;
    u32 r = x.u + 0x7FFFu + ((x.u >> 16) & 1u);
    return (u16)(r >> 16);
}

__device__ __forceinline__ u16 f2bf_fast(float f) {     // round-half-up (hot path)
    union { float f; u32 u; } x; x.f = f;
    return (u16)((x.u + 0x8000u) >> 16);
}

__device__ __forceinline__ void gload16(const u16* g, u16* l) {
    __builtin_amdgcn_global_load_lds(
        (const __attribute__((address_space(1))) void*)g,
        (__attribute__((address_space(3))) void*)l,
        16, 0, 0);
}

__device__ __forceinline__ f32x4 mfma16(bf16x8 a, bf16x8 b, f32x4 c) {
    return __builtin_amdgcn_mfma_f32_16x16x32_bf16(a, b, c, 0, 0, 0);
}

// ---------------- prep kernels ----------------

__global__ __launch_bounds__(256) void cvt_x(const float* __restrict__ in, u16* __restrict__ out, int n4) {
    int i = blockIdx.x * blockDim.x + threadIdx.x;
    if (i >= n4) return;
    float4 v = ((const float4*)in)[i];
    u16* o = out + (size_t)i * 4;
    o[0] = f2bf(v.x); o[1] = f2bf(v.y); o[2] = f2bf(v.z); o[3] = f2bf(v.w);
}

// all 4 weights in one launch; z selects the matrix
__global__ __launch_bounds__(256) void transpose_w4(const float* __restrict__ Wq, const float* __restrict__ Wk,
                                                    const float* __restrict__ Wv, const float* __restrict__ Wo,
                                                    u16* __restrict__ qkvt, u16* __restrict__ wot) {
    __shared__ float tile[32][33];
    const float* in;
    u16* out;
    if (blockIdx.z == 0)      { in = Wq; out = qkvt; }
    else if (blockIdx.z == 1) { in = Wk; out = qkvt + 1024 * 1024; }
    else if (blockIdx.z == 2) { in = Wv; out = qkvt + 2 * 1024 * 1024; }
    else                      { in = Wo; out = wot; }
    const int bx = blockIdx.x * 32, by = blockIdx.y * 32;
    const int tx = threadIdx.x & 31, ty4 = (threadIdx.x >> 5) * 4;
#pragma unroll
    for (int j = 0; j < 4; ++j)
        tile[ty4 + j][tx] = in[(size_t)(by + ty4 + j) * 1024 + bx + tx];
    __syncthreads();
#pragma unroll
    for (int j = 0; j < 4; ++j)
        out[(size_t)(bx + ty4 + j) * 1024 + by + tx] = f2bf(tile[tx][ty4 + j]);
}

__global__ __launch_bounds__(256) void pack_bias(const float* __restrict__ bq, const float* __restrict__ bk,
                                                 const float* __restrict__ bv, float* __restrict__ out) {
    int i = blockIdx.x * blockDim.x + threadIdx.x;
    if (i >= 3072) return;
    out[i] = (i < 1024) ? bq[i] : ((i < 2048) ? bk[i - 1024] : bv[i - 2048]);
}

// ---------------- GEMM: C[M x N] = A[M x K] @ Bt[N x K]^T + bias ----------------
template<int MODE>
__global__ __launch_bounds__(256) void gemm128(const u16* __restrict__ A, const u16* __restrict__ Bt,
                                               const float* __restrict__ bias,
                                               u16* __restrict__ oq, u16* __restrict__ ok, u16* __restrict__ ov,
                                               float* __restrict__ of, int K)
{
    __shared__ u16 As[128 * 32];
    __shared__ u16 Bs[128 * 32];

    const int n0 = blockIdx.x * 128;
    const int m0 = blockIdx.y * 128;
    const int t = threadIdx.x;
    const int w = t >> 6, lane = t & 63;
    const int g = lane >> 4, lr = lane & 15;
    const int wm = w >> 1, wn = w & 1;
    const int srow = lane >> 2;
    const int scol = (lane & 3) * 8;

    f32x4 acc[4][4] = {};

    for (int k0 = 0; k0 < K; k0 += 32) {
        __syncthreads();
#pragma unroll
        for (int i = 0; i < 2; ++i) {
            const int c = w + i * 4;
            const int mrow = c * 16 + srow;
            gload16(A  + (size_t)(m0 + mrow) * K + k0 + scol, &As[c * 512 + lane * 8]);
            gload16(Bt + (size_t)(n0 + mrow) * K + k0 + scol, &Bs[c * 512 + lane * 8]);
        }
        __syncthreads();
        bf16x8 af[4], bfr[4];
#pragma unroll
        for (int mi = 0; mi < 4; ++mi) af[mi]  = *(const bf16x8*)&As[(wm * 64 + mi * 16 + lr) * 32 + g * 8];
#pragma unroll
        for (int ni = 0; ni < 4; ++ni) bfr[ni] = *(const bf16x8*)&Bs[(wn * 64 + ni * 16 + lr) * 32 + g * 8];
#pragma unroll
        for (int mi = 0; mi < 4; ++mi)
#pragma unroll
            for (int ni = 0; ni < 4; ++ni)
                acc[mi][ni] = mfma16(af[mi], bfr[ni], acc[mi][ni]);
    }

#pragma unroll
    for (int mi = 0; mi < 4; ++mi) {
#pragma unroll
        for (int ni = 0; ni < 4; ++ni) {
            const int col = n0 + wn * 64 + ni * 16 + lr;
            const int row0 = m0 + wm * 64 + mi * 16 + g * 4;
            const float bs = bias[col];
            if (MODE == 0) {
                const int mat = col >> 10;
                const int nn = col & 1023;
                const int h = nn >> 6, d = nn & 63;
#pragma unroll
                for (int j = 0; j < 4; ++j) {
                    const int rr = row0 + j;
                    const int b = rr >> 11, ll = rr & 2047;
                    const int bh = b * 16 + h;
                    const float v = acc[mi][ni][j] + bs;
                    // Q pre-scaled by (1/8)*log2(e) so softmax runs in exp2 domain
                    if (mat == 0)      oq[((size_t)bh * 2048 + ll) * 64 + d] = f2bf(v * 0.1803368801111244f);
                    else if (mat == 1) ok[((size_t)bh * 2048 + ll) * 64 + d] = f2bf(v);
                    else               ov[((size_t)bh * 64 + d) * 2048 + ll] = f2bf(v);
                }
            } else {
#pragma unroll
                for (int j = 0; j < 4; ++j) {
                    const int rr = row0 + j;
                    of[(size_t)rr * 1024 + col] = acc[mi][ni][j] + bs;
                }
            }
        }
    }
}

// ---------------- flash attention (causal): swapped QK^T, in-lane softmax, P via LDS ----------------
// Q,K: [32 bh][2048][64] bf16 (Q pre-scaled by log2e/8).  Vt: [32 bh][64][2048] bf16.
// O: [b][l][1024] bf16.
// S^T = mfma(K,Q): lane (g,lr) reg j holds S[q=qw+lr][kloc=16ni+4g+j] -> softmax fully
// in-lane (15 fmax + 2 shfl). P is packed to bf16 pairs with verified bit-ops and written
// to LDS at its (q,kloc) coordinates (8x ds_write_b32, chunk-swizzled); the PV A-fragment
// is then read with the R4-proven b128 [row][8g+e] convention. No unproven layout is used.
__global__ __launch_bounds__(256) void attn(const u16* __restrict__ Q, const u16* __restrict__ Kg,
                                            const u16* __restrict__ Vt, u16* __restrict__ O)
{
    __shared__ u16 Ks[2][64 * 64];
    __shared__ u16 Vs[2][64 * 64];
    __shared__ u16 Ps[4][16 * 64];       // per-wave P tile [16 q][64 k], chunk-swizzled

    const int bh = blockIdx.x;
    const int qb = (int)gridDim.y - 1 - blockIdx.y;  // heavy q-blocks dispatch first
    const int q0 = qb * 64;
    const int t = threadIdx.x;
    const int w = t >> 6, lane = t & 63;
    const int g = lane >> 4, lr = lane & 15;
    const int qw = q0 + w * 16;
    const int sw = lr & 7;

    const u16* Qb = Q  + (size_t)bh * 2048 * 64;
    const u16* Kb = Kg + (size_t)bh * 2048 * 64;
    const u16* Vb = Vt + (size_t)bh * 64 * 2048;

    const bf16x8 qf0 = *(const bf16x8*)&Qb[(size_t)(qw + lr) * 64 + g * 8];
    const bf16x8 qf1 = *(const bf16x8*)&Qb[(size_t)(qw + lr) * 64 + 32 + g * 8];

    const short one = (short)0x3F80;                 // bf16 1.0
    const bf16x8 vones = {one, one, one, one, one, one, one, one};

    f32x4 oacc[4] = {};                              // C layout: q = qw + 4g+j, d = df*16+lr
    f32x4 lsacc = {};                                // row sums (P @ ones), same layout
    float mrun = -1e30f;                             // softmax state for q = qw + lr

    // bpermute addrs: lane (g,lr) pulls r for q=4g+j from lane 20g+j (lr'=4g+j)
    int bpaddr[4];
#pragma unroll
    for (int j = 0; j < 4; ++j) bpaddr[j] = (20 * g + j) * 4;

    // P-write addressing: lane (g,lr) writes pairs (kloc=16ni+4g+2jp, +1) to row lr.
    // word index wloc = 8ni+2g+jp; chunk c8 = 2ni + (g>>1); word-in-chunk = (2g+jp)&3.
    const int pw_base = lr * 64;                     // u16 offset of row lr
    const int g2h = g >> 1;
    const int wic2 = (2 * g) & 3;                    // word-in-chunk for jp=0 (jp adds 1)

    // T14 reg staging, double-buffered LDS, 1 barrier per tile
    bf16x8 kreg[2], vreg[2];
    const int srow0 = t >> 3, sch = t & 7;
    auto issue = [&](int kb) {
#pragma unroll
        for (int i = 0; i < 2; ++i) {
            const int row = srow0 + i * 32;
            kreg[i] = *(const bf16x8*)&Kb[(size_t)(kb * 64 + row) * 64 + sch * 8];
            vreg[i] = *(const bf16x8*)&Vb[(size_t)row * 2048 + kb * 64 + sch * 8];
        }
    };
    auto commit = [&](int buf) {
#pragma unroll
        for (int i = 0; i < 2; ++i) {
            const int row = srow0 + i * 32;
            const int chs = sch ^ (row & 7);
            *(bf16x8*)&Ks[buf][row * 64 + chs * 8] = kreg[i];
            *(bf16x8*)&Vs[buf][row * 64 + chs * 8] = vreg[i];
        }
    };

    issue(0);
    commit(0);

    for (int kb = 0; kb <= qb; ++kb) {
        const int cur = kb & 1;
        const int k0 = kb * 64;
        __syncthreads();                     // publishes LDS[cur]
        const bool more = (kb < qb);
        if (more) issue(kb + 1);             // global loads fly under QK + softmax

        // ---- S^T = K @ Q^T : lane holds S[q=qw+lr][kloc = 16ni+4g+j] ----
        f32x4 s[4] = {};
        __builtin_amdgcn_s_setprio(1);
#pragma unroll
        for (int ni = 0; ni < 4; ++ni) {
            const int row = ni * 16 + lr;
            bf16x8 kf0 = *(const bf16x8*)&Ks[cur][row * 64 + (g ^ sw) * 8];
            bf16x8 kf1 = *(const bf16x8*)&Ks[cur][row * 64 + ((4 + g) ^ sw) * 8];
            s[ni] = mfma16(kf0, qf0, s[ni]);
            s[ni] = mfma16(kf1, qf1, s[ni]);
        }
        __builtin_amdgcn_s_setprio(0);

        if (kb == qb) {                      // diagonal tile: causal mask (k > q)
            const int qq = qw + lr;
#pragma unroll
            for (int ni = 0; ni < 4; ++ni)
#pragma unroll
                for (int j = 0; j < 4; ++j)
                    if (k0 + ni * 16 + g * 4 + j > qq) s[ni][j] = -1e30f;
        }

        // ---- row max: 15 in-lane fmax + 2 shfl (row q spans lanes lr, lr+16, lr+32, lr+48) ----
        float pm = fmaxf(fmaxf(fmaxf(s[0][0], s[0][1]), fmaxf(s[0][2], s[0][3])),
                         fmaxf(fmaxf(s[1][0], s[1][1]), fmaxf(s[1][2], s[1][3])));
        pm = fmaxf(pm, fmaxf(fmaxf(fmaxf(s[2][0], s[2][1]), fmaxf(s[2][2], s[2][3])),
                             fmaxf(fmaxf(s[3][0], s[3][1]), fmaxf(s[3][2], s[3][3]))));
        pm = fmaxf(pm, __shfl_xor(pm, 16));
        pm = fmaxf(pm, __shfl_xor(pm, 32));

        // ---- defer-max (T13, THR=8 in exp2 domain => P <= 256) ----
        if (__any(pm > mrun + 8.f)) {
            const float mn = fmaxf(mrun, pm);
            const float r = __builtin_amdgcn_exp2f(mrun - mn);
            mrun = mn;
            const int ri = __float_as_int(r);
#pragma unroll
            for (int j = 0; j < 4; ++j) {
                const float ro = __int_as_float(__builtin_amdgcn_ds_bpermute(bpaddr[j], ri));
                lsacc[j] *= ro;
#pragma unroll
                for (int df = 0; df < 4; ++df) oacc[df][j] *= ro;
            }
        }

        // ---- P = exp2(S - m): pack bf16 pairs (bit-ops) and write to LDS (q,kloc) slots ----
#pragma unroll
        for (int ni = 0; ni < 4; ++ni) {
            const int c8 = 2 * ni + g2h;
#pragma unroll
            for (int jp = 0; jp < 2; ++jp) {
                const float plo = __builtin_amdgcn_exp2f(s[ni][2 * jp]     - mrun);
                const float phi = __builtin_amdgcn_exp2f(s[ni][2 * jp + 1] - mrun);
                const u32 pr = (u32)f2bf_fast(plo) | ((u32)f2bf_fast(phi) << 16);
                const int wic = wic2 + jp;                       // (2g+jp)&3 (2g&3 has bit0=0)
                *(u32*)&Ps[w][pw_base + (c8 ^ sw) * 8 + wic * 2] = pr;
            }
        }
        // P is per-wave private: lgkmcnt (compiler) orders write->read, no barrier

        if (more) commit(cur ^ 1);           // vmcnt wait on kreg/vreg, write other buffer

        // ---- O += P @ V ; l += P @ 1 : R4-proven b128 fragment reads ----
        const bf16x8 p0 = *(const bf16x8*)&Ps[w][lr * 64 + (g ^ sw) * 8];
        const bf16x8 p1 = *(const bf16x8*)&Ps[w][lr * 64 + ((4 + g) ^ sw) * 8];
        __builtin_amdgcn_s_setprio(1);
        lsacc = mfma16(p0, vones, lsacc);
        lsacc = mfma16(p1, vones, lsacc);
#pragma unroll
        for (int df = 0; df < 4; ++df) {
            const int row = df * 16 + lr;
            bf16x8 vf0 = *(const bf16x8*)&Vs[cur][row * 64 + (g ^ sw) * 8];
            bf16x8 vf1 = *(const bf16x8*)&Vs[cur][row * 64 + ((4 + g) ^ sw) * 8];
            oacc[df] = mfma16(p0, vf0, oacc[df]);
            oacc[df] = mfma16(p1, vf1, oacc[df]);
        }
        __builtin_amdgcn_s_setprio(0);
    }

    // epilogue: normalize by MFMA row sums; store to [b][l][h*64+d]
    const int b = bh >> 4, h = bh & 15;
#pragma unroll
    for (int j = 0; j < 4; ++j) {
        const float inv = 1.f / lsacc[j];
        const int l = qw + g * 4 + j;
#pragma unroll
        for (int df = 0; df < 4; ++df)
            O[((size_t)b * 2048 + l) * 1024 + h * 64 + df * 16 + lr] = f2bf(oacc[df][j] * inv);
    }
}

// ---------------- launch ----------------

extern "C" void kernel_launch(void* const* d_in, const int* in_sizes, int n_in,
                              void* d_out, int out_size, void* d_ws, size_t ws_size,
                              hipStream_t stream)
{
    const float* hs = (const float*)d_in[0];
    const float* Wq = (const float*)d_in[1];
    const float* bq = (const float*)d_in[2];
    const float* Wk = (const float*)d_in[3];
    const float* bk = (const float*)d_in[4];
    const float* Wv = (const float*)d_in[5];
    const float* bv = (const float*)d_in[6];
    const float* Wo = (const float*)d_in[7];
    const float* bo = (const float*)d_in[8];
    float* out = (float*)d_out;

    char* ws = (char*)d_ws;
    u16*   Xbf   = (u16*)(ws);                     // 8 MB, reused as Abuf after QKV GEMM
    u16*   Wqkvt = (u16*)(ws + (8ull  << 20));     // 6 MB
    u16*   Wot   = (u16*)(ws + (14ull << 20));     // 2 MB
    float* bqkv  = (float*)(ws + (16ull << 20));   // 12 KB
    u16*   Qbuf  = (u16*)(ws + (17ull << 20));     // 8 MB
    u16*   Kbuf  = (u16*)(ws + (25ull << 20));     // 8 MB
    u16*   Vtbuf = (u16*)(ws + (33ull << 20));     // 8 MB
    u16*   Abuf  = Xbf;                            // alias: X dead after QKV GEMM

    cvt_x<<<4096, 256, 0, stream>>>(hs, Xbf, 4096 * 1024 / 4);
    transpose_w4<<<dim3(32, 32, 4), 256, 0, stream>>>(Wq, Wk, Wv, Wo, Wqkvt, Wot);
    pack_bias<<<12, 256, 0, stream>>>(bq, bk, bv, bqkv);

    // QKV: [4096 x 3072]
    gemm128<0><<<dim3(24, 32), 256, 0, stream>>>(Xbf, Wqkvt, bqkv, Qbuf, Kbuf, Vtbuf, nullptr, 1024);
    // attention: grid (bh, qb), QBLK=64, heavy-first
    attn<<<dim3(32, 32), 256, 0, stream>>>(Qbuf, Kbuf, Vtbuf, Abuf);
    // output projection: [4096 x 1024] -> fp32 d_out
    gemm128<1><<<dim3(8, 32), 256, 0, stream>>>(Abuf, Wot, bo, nullptr, nullptr, nullptr, out, 1024);
}